// Round 16
// baseline (44.139 us; speedup 1.0000x reference)
//
#include <hip/hip_runtime.h>
#include <hip/hip_bf16.h>

namespace {

// may_alias: LDS stage is written as u64 (bf16x4 packs) and read as bf16x8;
// tbuf is written as float and read as f32x4.
typedef short bf16x8 __attribute__((ext_vector_type(8), may_alias));
typedef unsigned long long u64_ma __attribute__((may_alias));
typedef float f32x4_ma __attribute__((ext_vector_type(4), may_alias));
typedef __attribute__((ext_vector_type(16))) float f32x16;   // MFMA 32x32 acc

constexpr int kB = 32, kT = 16384, kCin = 32, kCout = 32;
constexpr int kL = 128;            // owned rows per chunk
constexpr int kK = 32;             // zero-state warm-up
constexpr int kChunks = kT / kL;   // 128
constexpr int kWpB = 4;            // waves per block
constexpr int kRS = 80;            // LDS bf16 row stride: 64B data + 16B pad
                                   // (bank start = 20*row mod 32, period 8 ->
                                   //  uniform 4-way b128 floor)
constexpr int kStageRows = 34;     // 32 rows + 2 halo rows
constexpr int kStageB = kStageRows * kRS;  // 2720 B per stage buffer
constexpr int kNT = 5;             // 1 warm-up tile + 4 owned tiles
constexpr int kTS = 36;            // transpose-buffer row stride (floats)
constexpr int kTBufF = 32 * kTS;   // 1152 floats

__device__ __forceinline__ unsigned bfbits(float f) {
  return (unsigned)__builtin_bit_cast(unsigned short, __float2bfloat16(f));
}

// R13's kernel + TRUE depth-2 prefetch: fully unrolled 5-tile loop with a
// static pf[2][5] register-group array (no copies — R12's fatal flaw was
// `c0 = n0` forcing a same-iteration vmcnt wait). Iteration k issues T(k+2),
// computes T(k), stashes T(k+1); first USE of T(k+1)'s registers (the stash)
// is 2 compute phases after issue, so the compiler's automatic counted vmcnt
// wait lands past the congested service time.
__global__ __launch_bounds__(256, 4) void mimo_mfma11(
    const float* __restrict__ u,        // [B, T, CIN]
    const float* __restrict__ x0,       // [B, 2, COUT]
    const float* __restrict__ a_coeff,  // [2, COUT]
    const float* __restrict__ b_coeff,  // [3, CIN, COUT]
    float* __restrict__ out)            // [B, T, COUT]
{
  __shared__ char stage[kWpB][2][kStageB];   // 21.25 KiB (double-buffered)
  __shared__ float tbf[kWpB][kTBufF];        // 18.0 KiB

  const int tidx = (int)threadIdx.x;
  const int lane = tidx & 63;
  const int col  = lane & 31;          // output channel / time-row within tile
  const int g    = lane >> 5;          // lane-half
  const int widx = tidx >> 6;
  const int wid  = (int)blockIdx.x * kWpB + widx;
  const int b     = wid >> 7;          // 0..31
  const int chunk = wid & (kChunks - 1);
  const int t0     = chunk * kL;
  const int tstart = t0 - kK;          // chunk 0 warms over zero-pad

  float* Tw = &tbf[widx][0];

  // B fragments: slot (g,j) of K-step (tau,h) = b_coeff[2-tau][16g+8h+j][col].
  // A uses the SAME slot->channel map, so the HW k-order cancels.
  bf16x8 Bf[3][2];
#pragma unroll
  for (int tau = 0; tau < 3; ++tau)
#pragma unroll
    for (int h = 0; h < 2; ++h) {
      const float* bp = b_coeff + (size_t)(2 - tau) * kCin * kCout
                        + (16 * g + 8 * h) * kCout + col;
      bf16x8 fr;
#pragma unroll
      for (int j = 0; j < 8; ++j)
        fr[j] = (short)__builtin_bit_cast(unsigned short, __float2bfloat16(bp[j * kCout]));
      Bf[tau][h] = fr;
    }

  const float a1 = a_coeff[col];
  const float a2 = a_coeff[kCout + col];
  // chunk-0 exact initial state, injected at the first owned tile (warm-up
  // over zero-padded u leaves the state at exactly 0 for chunk 0).
  float i1 = 0.f, i2 = 0.f;
  if (chunk == 0) {
    i1 = x0[(b * 2 + 1) * kCout + col];
    i2 = x0[(b * 2 + 0) * kCout + col];
  }
  float s1 = 0.f, s2 = 0.f;

  const float* ub = u + (size_t)b * kT * kCin;
  float* ob = out + (size_t)b * kT * kCout;

  // Coalesced stage load: f4-index f of a 34-row stage starting at rowbase.
  auto gload = [&](int rowbase, int f) -> float4 {
    const int grow = rowbase + (f >> 3);
    if (grow >= 0)
      return *(const float4*)(ub + (size_t)grow * kCin + ((f & 7) << 2));
    float4 z; z.x = 0.f; z.y = 0.f; z.z = 0.f; z.w = 0.f;
    return z;
  };
  // cvt f32x4 -> bf16x4 and ds_write_b64 into an 80B-stride stage buffer.
  auto stash = [&](char* S, int f, float4 v) {
    const unsigned lo = bfbits(v.x) | (bfbits(v.y) << 16);
    const unsigned hi = bfbits(v.z) | (bfbits(v.w) << 16);
    const unsigned long long q = ((unsigned long long)hi << 32) | lo;
    *(u64_ma*)(S + (f >> 3) * kRS + (f & 7) * 8) = q;
  };

  // Prefetch register groups: pf[parity][5]. All indices are compile-time
  // constants after full unroll (rule #20 — no scratch).
  float4 pf[2][5];

  // -------- prologue: issue T0 and T1, stash T0 into buf0 --------
  {
    const int rb0 = tstart - 2;            // T0 rows (negatives -> zeros)
    pf[0][0] = gload(rb0, lane);
    pf[0][1] = gload(rb0, lane + 64);
    pf[0][2] = gload(rb0, lane + 128);
    pf[0][3] = gload(rb0, lane + 192);
    if (lane < 16) pf[0][4] = gload(rb0, lane + 256);
    const int rb1 = tstart + 30;           // T1 rows
    pf[1][0] = gload(rb1, lane);
    pf[1][1] = gload(rb1, lane + 64);
    pf[1][2] = gload(rb1, lane + 128);
    pf[1][3] = gload(rb1, lane + 192);
    if (lane < 16) pf[1][4] = gload(rb1, lane + 256);
    // stash T0 (compiler auto-waits on T0's regs only; T1 stays in flight)
    char* S0 = &stage[widx][0][0];
    stash(S0, lane, pf[0][0]);
    stash(S0, lane + 64, pf[0][1]);
    stash(S0, lane + 128, pf[0][2]);
    stash(S0, lane + 192, pf[0][3]);
    if (lane < 16) stash(S0, lane + 256, pf[0][4]);
  }
  asm volatile("" ::: "memory");   // stage writes ordered before tile-0 reads

#pragma unroll
  for (int tile = 0; tile < kNT; ++tile) {
    const int tbase = tstart + 32 * tile;
    const bool owned = (tile >= 1);
    char* Scur = &stage[widx][tile & 1][0];

    // depth-2 issue: T(tile+2) into pf[tile&1] (freed by last iter's stash).
    if (tile + 2 < kNT) {
      const int rb = tstart - 2 + 32 * (tile + 2);
      pf[tile & 1][0] = gload(rb, lane);
      pf[tile & 1][1] = gload(rb, lane + 64);
      pf[tile & 1][2] = gload(rb, lane + 128);
      pf[tile & 1][3] = gload(rb, lane + 192);
      if (lane < 16) pf[tile & 1][4] = gload(rb, lane + 256);
    }

    // ---- FIR: 6x ds_read_b128 (bf16 direct) + 6 MFMAs ----
    f32x16 acc;
#pragma unroll
    for (int i = 0; i < 16; ++i) acc[i] = 0.f;
#pragma unroll
    for (int tau = 0; tau < 3; ++tau) {
      const char* rp = Scur + (col + tau) * kRS + 32 * g;
#pragma unroll
      for (int h = 0; h < 2; ++h) {
        const bf16x8 fa = *(const bf16x8*)(rp + 16 * h);
        acc = __builtin_amdgcn_mfma_f32_32x32x16_bf16(fa, Bf[tau][h], acc, 0, 0, 0);
      }
    }

    // chunk-0 exact state injection at the first owned tile.
    if (chunk == 0 && tile == 1) { s1 = i1; s2 = i2; }

    // ---- IIR per reg-quad (R11/R13-proven); results to LDS transpose buf.
    // Reg r (half gg) holds row (r&3) + 8*(r>>2) + 4*gg of the tile.
    float x1 = s1, x2 = s2;
#pragma unroll
    for (int q = 0; q < 4; ++q) {
      const float o0 = __shfl_xor(acc[4 * q + 0], 32);
      const float o1 = __shfl_xor(acc[4 * q + 1], 32);
      const float o2 = __shfl_xor(acc[4 * q + 2], 32);
      const float o3 = __shfl_xor(acc[4 * q + 3], 32);
      const float va0 = g ? o0 : acc[4 * q + 0];
      const float va1 = g ? o1 : acc[4 * q + 1];
      const float va2 = g ? o2 : acc[4 * q + 2];
      const float va3 = g ? o3 : acc[4 * q + 3];
      const float ya0 = fmaf(a1, x1,  fmaf(a2, x2,  va0));
      const float ya1 = fmaf(a1, ya0, fmaf(a2, x1,  va1));
      const float ya2 = fmaf(a1, ya1, fmaf(a2, ya0, va2));
      const float ya3 = fmaf(a1, ya2, fmaf(a2, ya1, va3));
      const float vb0 = g ? acc[4 * q + 0] : o0;
      const float vb1 = g ? acc[4 * q + 1] : o1;
      const float vb2 = g ? acc[4 * q + 2] : o2;
      const float vb3 = g ? acc[4 * q + 3] : o3;
      const float yb0 = fmaf(a1, ya3, fmaf(a2, ya2, vb0));
      const float yb1 = fmaf(a1, yb0, fmaf(a2, ya3, vb1));
      const float yb2 = fmaf(a1, yb1, fmaf(a2, yb0, vb2));
      const float yb3 = fmaf(a1, yb2, fmaf(a2, yb1, vb3));
      x2 = yb2; x1 = yb3;
      if (owned) {
        const int rb = 8 * q + 4 * g;   // lane half g writes rows rb..rb+3
        Tw[(rb + 0) * kTS + col] = g ? yb0 : ya0;
        Tw[(rb + 1) * kTS + col] = g ? yb1 : ya1;
        Tw[(rb + 2) * kTS + col] = g ? yb2 : ya2;
        Tw[(rb + 3) * kTS + col] = g ? yb3 : ya3;
      }
    }
    s1 = x1; s2 = x2;

    // ---- emit: 4x ds_read_b128 + 4x full-wave global_store_dwordx4 ----
    if (owned) {
      asm volatile("" ::: "memory");   // transpose writes before reads
#pragma unroll
      for (int p = 0; p < 4; ++p) {
        const f32x4_ma v = *(const f32x4_ma*)
            ((const char*)Tw + (8 * p + (lane >> 3)) * (kTS * 4) + (lane & 7) * 16);
        *(f32x4_ma*)(ob + (size_t)(tbase + 8 * p) * kCout + lane * 4) = v;
      }
      asm volatile("" ::: "memory");   // reads before next tile's writes
    }

    // ---- stash T(tile+1) into the other buffer. FIRST USE of pf[(tile+1)&1]
    // since its issue 2 iterations ago -> compiler's auto vmcnt is counted,
    // past the congested service window. Different buffer than Scur, so no
    // read/write ordering constraint within this iteration.
    if (tile + 1 < kNT) {
      char* Snxt = &stage[widx][(tile + 1) & 1][0];
      stash(Snxt, lane, pf[(tile + 1) & 1][0]);
      stash(Snxt, lane + 64, pf[(tile + 1) & 1][1]);
      stash(Snxt, lane + 128, pf[(tile + 1) & 1][2]);
      stash(Snxt, lane + 192, pf[(tile + 1) & 1][3]);
      if (lane < 16) stash(Snxt, lane + 256, pf[(tile + 1) & 1][4]);
      asm volatile("" ::: "memory");   // stash before next tile's ds_reads
    }
  }
}

}  // namespace

extern "C" void kernel_launch(void* const* d_in, const int* in_sizes, int n_in,
                              void* d_out, int out_size, void* d_ws, size_t ws_size,
                              hipStream_t stream) {
  const float* u  = (const float*)d_in[0];
  const float* x0 = (const float*)d_in[1];
  const float* a  = (const float*)d_in[2];
  const float* bb = (const float*)d_in[3];
  float* out = (float*)d_out;

  dim3 grid(kB * kChunks / kWpB);  // 4096 waves / 4 = 1024 blocks
  dim3 block(256);
  hipLaunchKernelGGL(mimo_mfma11, grid, block, 0, stream, u, x0, a, bb, out);
}

// Round 17
// 42.085 us; speedup vs baseline: 1.0488x; 1.0488x over previous
//
#include <hip/hip_runtime.h>
#include <hip/hip_bf16.h>

namespace {

// may_alias: LDS stage is written as u64 (bf16x4 packs) and read as bf16x8;
// tbuf is written as float and read as f32x4.
typedef short bf16x8 __attribute__((ext_vector_type(8), may_alias));
typedef unsigned long long u64_ma __attribute__((may_alias));
typedef float f32x4_ma __attribute__((ext_vector_type(4), may_alias));
typedef __attribute__((ext_vector_type(16))) float f32x16;   // MFMA 32x32 acc

constexpr int kB = 32, kT = 16384, kCin = 32, kCout = 32;
constexpr int kL = 128;            // owned rows per chunk
constexpr int kK = 32;             // zero-state warm-up
constexpr int kChunks = kT / kL;   // 128
constexpr int kWpB = 4;            // waves per block
constexpr int kRS = 80;            // LDS bf16 row stride: 64B data + 16B pad
                                   // (bank start = 20*row mod 32, period 8 ->
                                   //  uniform 4-way b128 floor)
constexpr int kSRows = 66;         // stage rows per phase (2 tiles + 2 halo)
constexpr int kStageB = kSRows * kRS;  // 5280 B per wave
constexpr int kTS = 36;            // transpose-buffer row stride (floats)
constexpr int kTBufF = 32 * kTS;   // 1152 floats

__device__ __forceinline__ unsigned bfbits(float f) {
  return (unsigned)__builtin_bit_cast(unsigned short, __float2bfloat16(f));
}

// R13's kernel with the phase structure halved: 3 phases x 9-load bursts
// (66-row stages, 2 tiles computed per phase) instead of 5 phases x 5-load
// bursts. Occupancy (4 blocks/CU), staging layout, IIR, and store path are
// IDENTICAL to R13 — clean isolation of burst-depth / phase-count.
__global__ __launch_bounds__(256, 4) void mimo_mfma12(
    const float* __restrict__ u,        // [B, T, CIN]
    const float* __restrict__ x0,       // [B, 2, COUT]
    const float* __restrict__ a_coeff,  // [2, COUT]
    const float* __restrict__ b_coeff,  // [3, CIN, COUT]
    float* __restrict__ out)            // [B, T, COUT]
{
  __shared__ char stage[kWpB][kStageB];   // 20.6 KiB
  __shared__ float tbf[kWpB][kTBufF];     // 18.0 KiB  (38.6 KiB -> 4 blk/CU)

  const int tidx = (int)threadIdx.x;
  const int lane = tidx & 63;
  const int col  = lane & 31;          // output channel / time-row within tile
  const int g    = lane >> 5;          // lane-half
  const int widx = tidx >> 6;
  const int wid  = (int)blockIdx.x * kWpB + widx;
  const int b     = wid >> 7;          // 0..31
  const int chunk = wid & (kChunks - 1);
  const int t0    = chunk * kL;

  char* Sw = &stage[widx][0];
  float* Tw = &tbf[widx][0];

  // B fragments: slot (g,j) of K-step (tau,h) = b_coeff[2-tau][16g+8h+j][col].
  // A uses the SAME slot->channel map, so the HW k-order cancels.
  bf16x8 Bf[3][2];
#pragma unroll
  for (int tau = 0; tau < 3; ++tau)
#pragma unroll
    for (int h = 0; h < 2; ++h) {
      const float* bp = b_coeff + (size_t)(2 - tau) * kCin * kCout
                        + (16 * g + 8 * h) * kCout + col;
      bf16x8 fr;
#pragma unroll
      for (int j = 0; j < 8; ++j)
        fr[j] = (short)__builtin_bit_cast(unsigned short, __float2bfloat16(bp[j * kCout]));
      Bf[tau][h] = fr;
    }

  const float a1 = a_coeff[col];
  const float a2 = a_coeff[kCout + col];
  // chunk-0 exact initial state, injected after the warm-up tile (warm-up
  // over zero-padded u leaves the state at exactly 0 for chunk 0).
  float i1 = 0.f, i2 = 0.f;
  if (chunk == 0) {
    i1 = x0[(b * 2 + 1) * kCout + col];
    i2 = x0[(b * 2 + 0) * kCout + col];
  }
  float s1 = 0.f, s2 = 0.f;

  const float* ub = u + (size_t)b * kT * kCin;
  float* ob = out + (size_t)b * kT * kCout;

  // Coalesced stage load: f4-index f of a stage starting at rowbase.
  auto gload = [&](int rowbase, int f) -> float4 {
    const int grow = rowbase + (f >> 3);
    if (grow >= 0)
      return *(const float4*)(ub + (size_t)grow * kCin + ((f & 7) << 2));
    float4 z; z.x = 0.f; z.y = 0.f; z.z = 0.f; z.w = 0.f;
    return z;
  };
  // cvt f32x4 -> bf16x4 and ds_write_b64 into the 80B-stride stage.
  auto stash = [&](int f, float4 v) {
    const unsigned lo = bfbits(v.x) | (bfbits(v.y) << 16);
    const unsigned hi = bfbits(v.z) | (bfbits(v.w) << 16);
    const unsigned long long q = ((unsigned long long)hi << 32) | lo;
    *(u64_ma*)(Sw + (f >> 3) * kRS + (f & 7) * 8) = q;
  };

  // One tile of FIR + IIR + (optional) transpose-store. Stage row offset roff
  // is 0 or 32 (both ≡ 0 mod 8 -> identical bank behavior).
  auto do_tile = [&](int roff, int tbase, bool owned) {
    f32x16 acc;
#pragma unroll
    for (int i = 0; i < 16; ++i) acc[i] = 0.f;
#pragma unroll
    for (int tau = 0; tau < 3; ++tau) {
      const char* rp = Sw + (roff + col + tau) * kRS + 32 * g;
#pragma unroll
      for (int h = 0; h < 2; ++h) {
        const bf16x8 fa = *(const bf16x8*)(rp + 16 * h);
        acc = __builtin_amdgcn_mfma_f32_32x32x16_bf16(fa, Bf[tau][h], acc, 0, 0, 0);
      }
    }
    // IIR per reg-quad; reg r (half gg) holds row (r&3) + 8*(r>>2) + 4*gg.
    float x1 = s1, x2 = s2;
#pragma unroll
    for (int q = 0; q < 4; ++q) {
      const float o0 = __shfl_xor(acc[4 * q + 0], 32);
      const float o1 = __shfl_xor(acc[4 * q + 1], 32);
      const float o2 = __shfl_xor(acc[4 * q + 2], 32);
      const float o3 = __shfl_xor(acc[4 * q + 3], 32);
      const float va0 = g ? o0 : acc[4 * q + 0];
      const float va1 = g ? o1 : acc[4 * q + 1];
      const float va2 = g ? o2 : acc[4 * q + 2];
      const float va3 = g ? o3 : acc[4 * q + 3];
      const float ya0 = fmaf(a1, x1,  fmaf(a2, x2,  va0));
      const float ya1 = fmaf(a1, ya0, fmaf(a2, x1,  va1));
      const float ya2 = fmaf(a1, ya1, fmaf(a2, ya0, va2));
      const float ya3 = fmaf(a1, ya2, fmaf(a2, ya1, va3));
      const float vb0 = g ? acc[4 * q + 0] : o0;
      const float vb1 = g ? acc[4 * q + 1] : o1;
      const float vb2 = g ? acc[4 * q + 2] : o2;
      const float vb3 = g ? acc[4 * q + 3] : o3;
      const float yb0 = fmaf(a1, ya3, fmaf(a2, ya2, vb0));
      const float yb1 = fmaf(a1, yb0, fmaf(a2, ya3, vb1));
      const float yb2 = fmaf(a1, yb1, fmaf(a2, yb0, vb2));
      const float yb3 = fmaf(a1, yb2, fmaf(a2, yb1, vb3));
      x2 = yb2; x1 = yb3;
      if (owned) {
        const int rb = 8 * q + 4 * g;   // lane half g writes rows rb..rb+3
        Tw[(rb + 0) * kTS + col] = g ? yb0 : ya0;
        Tw[(rb + 1) * kTS + col] = g ? yb1 : ya1;
        Tw[(rb + 2) * kTS + col] = g ? yb2 : ya2;
        Tw[(rb + 3) * kTS + col] = g ? yb3 : ya3;
      }
    }
    s1 = x1; s2 = x2;
    if (owned) {
      asm volatile("" ::: "memory");   // transpose writes before reads
#pragma unroll
      for (int p = 0; p < 4; ++p) {
        const f32x4_ma v = *(const f32x4_ma*)
            ((const char*)Tw + (8 * p + (lane >> 3)) * (kTS * 4) + (lane & 7) * 16);
        *(f32x4_ma*)(ob + (size_t)(tbase + 8 * p) * kCout + lane * 4) = v;
      }
      asm volatile("" ::: "memory");   // reads before next tile's writes
    }
  };

  // -------- prologue: stage S0 = rows [t0-34, t0+32)  (528 f4) --------
  {
    const int rb = t0 - 34;            // negative rows staged as zeros
    float4 p0 = gload(rb, lane);
    float4 p1 = gload(rb, lane + 64);
    float4 p2 = gload(rb, lane + 128);
    float4 p3 = gload(rb, lane + 192);
    float4 p4 = gload(rb, lane + 256);
    float4 p5 = gload(rb, lane + 320);
    float4 p6 = gload(rb, lane + 384);
    float4 p7 = gload(rb, lane + 448);
    float4 p8;
    if (lane < 16) p8 = gload(rb, lane + 512);
    stash(lane, p0);       stash(lane + 64, p1);
    stash(lane + 128, p2); stash(lane + 192, p3);
    stash(lane + 256, p4); stash(lane + 320, p5);
    stash(lane + 384, p6); stash(lane + 448, p7);
    if (lane < 16) stash(lane + 512, p8);
  }
  asm volatile("" ::: "memory");   // stage writes ordered before phase-0 reads

  // -------- phase 0: issue S1 burst; warm tile + T1; stash S1 --------
  float4 n0, n1, n2, n3, n4, n5, n6, n7, n8;
  {
    const int rb = t0 + 30;            // S1 = rows [t0+30, t0+96)
    n0 = gload(rb, lane);
    n1 = gload(rb, lane + 64);
    n2 = gload(rb, lane + 128);
    n3 = gload(rb, lane + 192);
    n4 = gload(rb, lane + 256);
    n5 = gload(rb, lane + 320);
    n6 = gload(rb, lane + 384);
    n7 = gload(rb, lane + 448);
    if (lane < 16) n8 = gload(rb, lane + 512);
  }
  do_tile(0, t0 - 32, false);          // warm-up tile (state only)
  if (chunk == 0) { s1 = i1; s2 = i2; }
  do_tile(32, t0, true);               // T1
  asm volatile("" ::: "memory");       // phase-0 ds_reads issue first
  stash(lane, n0);       stash(lane + 64, n1);
  stash(lane + 128, n2); stash(lane + 192, n3);
  stash(lane + 256, n4); stash(lane + 320, n5);
  stash(lane + 384, n6); stash(lane + 448, n7);
  if (lane < 16) stash(lane + 512, n8);
  asm volatile("" ::: "memory");       // refill before phase-1 ds_reads

  // -------- phase 1: issue S2 burst (34 rows); T2 + T3; stash S2 --------
  float4 m0, m1, m2, m3, m4;
  {
    const int rb = t0 + 94;            // S2 = rows [t0+94, t0+128)
    m0 = gload(rb, lane);
    m1 = gload(rb, lane + 64);
    m2 = gload(rb, lane + 128);
    m3 = gload(rb, lane + 192);
    if (lane < 16) m4 = gload(rb, lane + 256);
  }
  do_tile(0, t0 + 32, true);           // T2
  do_tile(32, t0 + 64, true);          // T3
  asm volatile("" ::: "memory");
  stash(lane, m0);       stash(lane + 64, m1);
  stash(lane + 128, m2); stash(lane + 192, m3);
  if (lane < 16) stash(lane + 256, m4);
  asm volatile("" ::: "memory");

  // -------- phase 2: T4 --------
  do_tile(0, t0 + 96, true);
}

}  // namespace

extern "C" void kernel_launch(void* const* d_in, const int* in_sizes, int n_in,
                              void* d_out, int out_size, void* d_ws, size_t ws_size,
                              hipStream_t stream) {
  const float* u  = (const float*)d_in[0];
  const float* x0 = (const float*)d_in[1];
  const float* a  = (const float*)d_in[2];
  const float* bb = (const float*)d_in[3];
  float* out = (float*)d_out;

  dim3 grid(kB * kChunks / kWpB);  // 4096 waves / 4 = 1024 blocks
  dim3 block(256);
  hipLaunchKernelGGL(mimo_mfma12, grid, block, 0, stream, u, x0, a, bb, out);
}

// Round 18
// 28.831 us; speedup vs baseline: 1.5310x; 1.4597x over previous
//
#include <hip/hip_runtime.h>
#include <hip/hip_bf16.h>

namespace {

// may_alias everywhere LDS/out is accessed through more than one type.
typedef short bf16x8 __attribute__((ext_vector_type(8), may_alias));
typedef unsigned long long u64_ma __attribute__((may_alias));
typedef float f32x4_ma __attribute__((ext_vector_type(4), may_alias));
typedef __attribute__((ext_vector_type(16))) float f32x16;   // MFMA 32x32 acc

constexpr int kB = 32, kT = 16384, kCin = 32, kCout = 32;
constexpr int kL = 128;            // owned rows per chunk
constexpr int kK = 32;             // zero-state warm-up
constexpr int kChunks = kT / kL;   // 128
constexpr int kWpB = 4;            // waves per block
constexpr int kRS = 80;            // LDS bf16 row stride: 64B data + 16B pad
constexpr int kStageRows = 34;     // 32 rows + 2 halo rows
constexpr int kStageB = kStageRows * kRS;  // 2720 B per stage
constexpr int kNT = 5;             // 1 warm-up tile + 4 owned tiles
constexpr int kTS = 36;            // transpose-buffer row stride (floats)
constexpr int kTBufB = 32 * kTS * 4;       // 4608 B per wave

__device__ __forceinline__ unsigned bfbits(float f) {
  return (unsigned)__builtin_bit_cast(unsigned short, __float2bfloat16(f));
}

// R13 (best, 29.4 us) with ONE change: the 4 transposed output stores are
// NON-TEMPORAL (nt flag -> stream past L2). Theory: write-allocating stores
// were evicting u-halo lines from L2 (R16/R17 counter signature: FETCH and
// WRITE balloon together when in-flight traffic grows); freeing L2 for the
// read stream should lift the ~3.6 TB/s plateau.
__global__ __launch_bounds__(256, 4) void mimo_mfma13(
    const float* __restrict__ u,        // [B, T, CIN]
    const float* __restrict__ x0,       // [B, 2, COUT]
    const float* __restrict__ a_coeff,  // [2, COUT]
    const float* __restrict__ b_coeff,  // [3, CIN, COUT]
    float* __restrict__ out)            // [B, T, COUT]
{
  __shared__ char stage[kWpB][kStageB];   // 10.6 KiB
  __shared__ char tbuf[kWpB][kTBufB];     // 18.0 KiB

  const int tidx = (int)threadIdx.x;
  const int lane = tidx & 63;
  const int col  = lane & 31;          // output channel / time-row within tile
  const int g    = lane >> 5;          // lane-half
  const int widx = tidx >> 6;
  const int wid  = (int)blockIdx.x * kWpB + widx;
  const int b     = wid >> 7;          // 0..31
  const int chunk = wid & (kChunks - 1);
  const int t0     = chunk * kL;
  const int tstart = t0 - kK;          // unified: chunk 0 warms over zero-pad

  char* Sw = &stage[widx][0];
  float* Tw = (float*)&tbuf[widx][0];

  // B fragments: slot (g,j) of K-step (tau,h) = b_coeff[2-tau][16g+8h+j][col].
  // A uses the SAME slot->channel map, so the HW k-order cancels.
  bf16x8 Bf[3][2];
#pragma unroll
  for (int tau = 0; tau < 3; ++tau)
#pragma unroll
    for (int h = 0; h < 2; ++h) {
      const float* bp = b_coeff + (size_t)(2 - tau) * kCin * kCout
                        + (16 * g + 8 * h) * kCout + col;
      bf16x8 fr;
#pragma unroll
      for (int j = 0; j < 8; ++j)
        fr[j] = (short)__builtin_bit_cast(unsigned short, __float2bfloat16(bp[j * kCout]));
      Bf[tau][h] = fr;
    }

  const float a1 = a_coeff[col];
  const float a2 = a_coeff[kCout + col];
  // chunk-0 exact initial state, injected at the first owned tile (warm-up
  // over zero-padded u leaves the state at exactly 0 for chunk 0).
  float i1 = 0.f, i2 = 0.f;
  if (chunk == 0) {
    i1 = x0[(b * 2 + 1) * kCout + col];
    i2 = x0[(b * 2 + 0) * kCout + col];
  }
  float s1 = 0.f, s2 = 0.f;

  const float* ub = u + (size_t)b * kT * kCin;
  float* ob = out + (size_t)b * kT * kCout;

  // Coalesced stage load: f4-index f of a 34-row stage starting at rowbase.
  auto gload = [&](int rowbase, int f) -> float4 {
    const int grow = rowbase + (f >> 3);
    if (grow >= 0)
      return *(const float4*)(ub + (size_t)grow * kCin + ((f & 7) << 2));
    float4 z; z.x = 0.f; z.y = 0.f; z.z = 0.f; z.w = 0.f;
    return z;
  };
  // cvt f32x4 -> bf16x4 and ds_write_b64 into the 80B-stride stage.
  auto stash = [&](int f, float4 v) {
    const unsigned lo = bfbits(v.x) | (bfbits(v.y) << 16);
    const unsigned hi = bfbits(v.z) | (bfbits(v.w) << 16);
    const unsigned long long q = ((unsigned long long)hi << 32) | lo;
    *(u64_ma*)(Sw + (f >> 3) * kRS + (f & 7) * 8) = q;
  };

  // -------- prologue: stage rows [tstart-2, tstart+32) --------
  {
    const int rowbase = tstart - 2;   // negative rows staged as zeros
    float4 p0 = gload(rowbase, lane);
    float4 p1 = gload(rowbase, lane + 64);
    float4 p2 = gload(rowbase, lane + 128);
    float4 p3 = gload(rowbase, lane + 192);
    float4 p4;
    if (lane < 16) p4 = gload(rowbase, lane + 256);
    stash(lane, p0);
    stash(lane + 64, p1);
    stash(lane + 128, p2);
    stash(lane + 192, p3);
    if (lane < 16) stash(lane + 256, p4);
  }
  asm volatile("" ::: "memory");   // stage writes ordered before tile-0 reads

#pragma unroll
  for (int tile = 0; tile < kNT; ++tile) {
    const int tbase = tstart + 32 * tile;
    const bool last = (tile + 1 == kNT);
    const bool owned = (tile >= 1);      // tile 0 is the warm-up tile

    // issue-early: next stage's coalesced global loads fly during compute.
    float4 n0, n1, n2, n3, n4;
    if (!last) {
      const int rowbase = tbase + 30;   // (tbase+32) - 2
      n0 = gload(rowbase, lane);
      n1 = gload(rowbase, lane + 64);
      n2 = gload(rowbase, lane + 128);
      n3 = gload(rowbase, lane + 192);
      if (lane < 16) n4 = gload(rowbase, lane + 256);
    }

    // ---- FIR: 6x ds_read_b128 (bf16 direct) + 6 MFMAs ----
    f32x16 acc;
#pragma unroll
    for (int i = 0; i < 16; ++i) acc[i] = 0.f;
#pragma unroll
    for (int tau = 0; tau < 3; ++tau) {
      const char* rp = Sw + (col + tau) * kRS + 32 * g;
#pragma unroll
      for (int h = 0; h < 2; ++h) {
        const bf16x8 fa = *(const bf16x8*)(rp + 16 * h);
        acc = __builtin_amdgcn_mfma_f32_32x32x16_bf16(fa, Bf[tau][h], acc, 0, 0, 0);
      }
    }

    // chunk-0 exact state injection at the first owned tile.
    if (chunk == 0 && tile == 1) { s1 = i1; s2 = i2; }

    // ---- IIR per reg-quad (R11-proven chain); results go to the LDS
    // transpose buffer. Lane (col,g) writes rows 8q+4g+0..3.
    // Reg r (half gg) holds row (r&3) + 8*(r>>2) + 4*gg of the tile.
    float x1 = s1, x2 = s2;
#pragma unroll
    for (int q = 0; q < 4; ++q) {
      const float o0 = __shfl_xor(acc[4 * q + 0], 32);
      const float o1 = __shfl_xor(acc[4 * q + 1], 32);
      const float o2 = __shfl_xor(acc[4 * q + 2], 32);
      const float o3 = __shfl_xor(acc[4 * q + 3], 32);
      const float va0 = g ? o0 : acc[4 * q + 0];
      const float va1 = g ? o1 : acc[4 * q + 1];
      const float va2 = g ? o2 : acc[4 * q + 2];
      const float va3 = g ? o3 : acc[4 * q + 3];
      const float ya0 = fmaf(a1, x1,  fmaf(a2, x2,  va0));
      const float ya1 = fmaf(a1, ya0, fmaf(a2, x1,  va1));
      const float ya2 = fmaf(a1, ya1, fmaf(a2, ya0, va2));
      const float ya3 = fmaf(a1, ya2, fmaf(a2, ya1, va3));
      const float vb0 = g ? acc[4 * q + 0] : o0;
      const float vb1 = g ? acc[4 * q + 1] : o1;
      const float vb2 = g ? acc[4 * q + 2] : o2;
      const float vb3 = g ? acc[4 * q + 3] : o3;
      const float yb0 = fmaf(a1, ya3, fmaf(a2, ya2, vb0));
      const float yb1 = fmaf(a1, yb0, fmaf(a2, ya3, vb1));
      const float yb2 = fmaf(a1, yb1, fmaf(a2, yb0, vb2));
      const float yb3 = fmaf(a1, yb2, fmaf(a2, yb1, vb3));
      x2 = yb2; x1 = yb3;
      if (owned) {
        const int rb = 8 * q + 4 * g;   // lane half g writes rows rb..rb+3
        Tw[(rb + 0) * kTS + col] = g ? yb0 : ya0;
        Tw[(rb + 1) * kTS + col] = g ? yb1 : ya1;
        Tw[(rb + 2) * kTS + col] = g ? yb2 : ya2;
        Tw[(rb + 3) * kTS + col] = g ? yb3 : ya3;
      }
    }
    s1 = x1; s2 = x2;

    // ---- emit: 4x ds_read_b128 + 4x full-wave NON-TEMPORAL dwordx4 stores.
    // nt stores stream past L2 -> L2 stays dedicated to the u read stream.
    if (owned) {
      asm volatile("" ::: "memory");   // transpose writes before reads
#pragma unroll
      for (int p = 0; p < 4; ++p) {
        const f32x4_ma v = *(const f32x4_ma*)
            ((const char*)Tw + (8 * p + (lane >> 3)) * (kTS * 4) + (lane & 7) * 16);
        __builtin_nontemporal_store(
            v, (f32x4_ma*)(ob + (size_t)(tbase + 8 * p) * kCout + lane * 4));
      }
      asm volatile("" ::: "memory");   // reads before next tile's writes
    }

    // write-late stage refill (wave-local, in-order DS).
    if (!last) {
      asm volatile("" ::: "memory");   // this tile's ds_reads issue first
      stash(lane, n0);
      stash(lane + 64, n1);
      stash(lane + 128, n2);
      stash(lane + 192, n3);
      if (lane < 16) stash(lane + 256, n4);
      asm volatile("" ::: "memory");   // refill before next tile's ds_reads
    }
  }
}

}  // namespace

extern "C" void kernel_launch(void* const* d_in, const int* in_sizes, int n_in,
                              void* d_out, int out_size, void* d_ws, size_t ws_size,
                              hipStream_t stream) {
  const float* u  = (const float*)d_in[0];
  const float* x0 = (const float*)d_in[1];
  const float* a  = (const float*)d_in[2];
  const float* bb = (const float*)d_in[3];
  float* out = (float*)d_out;

  dim3 grid(kB * kChunks / kWpB);  // 4096 waves / 4 = 1024 blocks
  dim3 block(256);
  hipLaunchKernelGGL(mimo_mfma13, grid, block, 0, stream, u, x0, a, bb, out);
}